// Round 2
// baseline (814.976 us; speedup 1.0000x reference)
//
#include <hip/hip_runtime.h>
#include <hip/hip_bf16.h>
#include <stdint.h>

#define B_ 4
#define H_ 160
#define W_ 160
#define HW_ 25600
#define PH_ 162
#define PHW_ 26244   // 162*162

typedef __hip_bfloat16 bf16;
typedef __attribute__((ext_vector_type(8))) short bf16x8;
typedef __attribute__((ext_vector_type(4))) float f32x4;

// ---------------- static workspace (module .bss) ----------------
// Padded NHWC bf16 activation buffers: [B][162][162][64], borders stay zero.
__device__ float g_CO[22118400];              // (4,216,160,160) NCHW f32; mask pre-sigmoided
__device__ __align__(16) bf16 g_P1[6718464];  // Xnbr  (padded NHWC bf16 of nbr)
__device__ __align__(16) bf16 g_P2[6718464];  // Xref
__device__ __align__(16) bf16 g_P3[6718464];  // A1
__device__ __align__(16) bf16 g_P4[6718464];  // A2
__device__ __align__(16) bf16 g_P5[6718464];  // F1 (dcn1 out / dcn2 x / coff1 in)
__device__ __align__(16) bf16 g_WB[516096];   // conv weights, fragment order
__device__ __align__(16) bf16 g_WD[73728];    // 2 x dcn weights, frag, K-permuted

__device__ __forceinline__ bf16* pbuf(int id) {
  if (id == 1) return g_P1;
  if (id == 2) return g_P2;
  if (id == 3) return g_P3;
  if (id == 4) return g_P4;
  return g_P5;
}

// ---------------- weight prep: conv fragment order ----------------
// layout [cc][tap][nt(NTPB)][lane(64)][j(8)]  (NB=1 everywhere now)
__global__ void prep_wfrag(const float* __restrict__ src, int off,
                           int OC, int CIN, int NB, int NTPB) {
  int i = blockIdx.x * 256 + threadIdx.x;
  int CC = CIN >> 5;
  int total = NB * CC * 9 * NTPB * 512;
  if (i >= total) return;
  int j = i & 7;
  int t = i >> 3;
  int lane = t & 63; t >>= 6;
  int nt = t % NTPB; t /= NTPB;
  int tap = t % 9; t /= 9;
  int cc = t % CC; int nb = t / CC;
  int oc = nb * (NTPB * 16) + nt * 16 + (lane & 15);
  int ci = cc * 32 + (lane >> 4) * 8 + j;
  float v = (oc < OC) ? src[(oc * CIN + ci) * 9 + tap] : 0.f;
  g_WB[off + i] = __float2bfloat16(v);
}

// dcn weights -> frag order with K-permutation k' = g*72 + kk*8 + c
__global__ void prep_wdcnfrag(const float* __restrict__ src, int off) {
  int i = blockIdx.x * 256 + threadIdx.x;
  if (i >= 36864) return;
  int j = i & 7;
  int t = i >> 3;
  int lane = t & 63; t >>= 6;
  int nt = t & 3; int kc = t >> 2;
  int kp = kc * 32 + (lane >> 4) * 8 + j;
  int oc = nt * 16 + (lane & 15);
  int g = kp / 72, r = kp - g * 72;
  int kk = r >> 3, c = r & 7;
  g_WD[off + i] = __float2bfloat16(src[oc * 576 + g * 72 + c * 9 + kk]);
}

// ---------------- NCHW f32 -> padded NHWC bf16 (64 ch) ----------------
// grid (160, B): one image row per block.
__global__ __launch_bounds__(256)
void nchw2nhwc_pad(const float* __restrict__ in, int out_id) {
  __shared__ float T[64][161];
  int tid = threadIdx.x;
  int y = blockIdx.x, b = blockIdx.y;
#pragma unroll
  for (int it = 0; it < 10; ++it) {
    int i = it * 256 + tid;                 // 2560 float4 loads
    int c = i / 40, xq = i - c * 40;
    float4 v = *(const float4*)&in[((size_t)(b * 64 + c) * H_ + y) * W_ + xq * 4];
    T[c][xq * 4 + 0] = v.x; T[c][xq * 4 + 1] = v.y;
    T[c][xq * 4 + 2] = v.z; T[c][xq * 4 + 3] = v.w;
  }
  __syncthreads();
  bf16* ob = pbuf(out_id) + ((size_t)b * PHW_ + (size_t)(y + 1) * PH_ + 1) * 64;
#pragma unroll
  for (int it = 0; it < 5; ++it) {
    int i = it * 256 + tid;                 // 1280 8-ch chunks
    int px = i >> 3, c0 = (i & 7) * 8;
    bf16 t[8];
#pragma unroll
    for (int j = 0; j < 8; ++j) t[j] = __float2bfloat16(T[c0 + j][px]);
    *(uint4*)(ob + (size_t)px * 64 + c0) = *(const uint4*)t;
  }
}

// ---------------- barrier-free implicit-GEMM conv3x3 (NHWC bf16) ----------------
// Block: 2 rows x 32 px, 4 waves. Wave w owns oc chunks [w*OCH .. w*OCH+OCH).
// A-operand = weights (lane&15 = oc, k-chunk by lane>>4) -> D rows = oc (4
// consecutive per lane), D cols = px -> packed NHWC stores, no LDS at all.
// MODE 0: lrelu -> padded NHWC bf16 out.  MODE 1: CO out, NCHW f32, sigmoid oc>=144.
template<int CC, int OCH, int MODE>
__global__ __launch_bounds__(256, 4)
void conv_nhwc(int in1_id, int in2_id, int ccsplit, int woff,
               const float* __restrict__ bias, int out_id)
{
  int tid = threadIdx.x;
  int w = tid >> 6, L = tid & 63, lm = L & 15;
  int k0 = (L >> 4) * 8;
  int bx = blockIdx.x;
  int b = blockIdx.y;
  int y0 = (bx / 5) * 2, x0 = (bx % 5) * 32;
  const bf16* s1 = pbuf(in1_id) + (size_t)b * PHW_ * 64;
  const bf16* s2 = pbuf(in2_id) + (size_t)b * PHW_ * 64;
  const bf16* wl = g_WB + woff + L * 8;
  constexpr int NTPB = 4 * OCH;

  f32x4 acc[4][OCH];
#pragma unroll
  for (int nf = 0; nf < 4; ++nf)
#pragma unroll
    for (int oh = 0; oh < OCH; ++oh) acc[nf][oh] = (f32x4)0.f;

#pragma unroll
  for (int cc = 0; cc < CC; ++cc) {
    const bf16* sb = (cc < ccsplit) ? (s1 + cc * 32) : (s2 + (cc - ccsplit) * 32);
#pragma unroll
    for (int tap = 0; tap < 9; ++tap) {
      const int dy = tap / 3, dx = tap - dy * 3;
      const int ks = cc * 9 + tap;
      bf16x8 af[4];
#pragma unroll
      for (int nf = 0; nf < 4; ++nf) {
        int ri = nf >> 1, ci = nf & 1;
        af[nf] = *(const bf16x8*)(sb +
            (size_t)((y0 + ri + dy) * PH_ + x0 + ci * 16 + dx + lm) * 64 + k0);
      }
#pragma unroll
      for (int oh = 0; oh < OCH; ++oh) {
        bf16x8 wf = *(const bf16x8*)(wl + (size_t)(ks * NTPB + w * OCH + oh) * 512);
#pragma unroll
        for (int nf = 0; nf < 4; ++nf)
          acc[nf][oh] = __builtin_amdgcn_mfma_f32_16x16x32_bf16(wf, af[nf], acc[nf][oh], 0, 0, 0);
      }
    }
  }

  int r4 = (L >> 4) * 4;
  if (MODE == 0) {
    bf16* ob = pbuf(out_id) + (size_t)b * PHW_ * 64;
    int ocb = w * 16 + r4;
#pragma unroll
    for (int nf = 0; nf < 4; ++nf) {
      int ri = nf >> 1, ci = nf & 1;
      size_t pix = (size_t)((y0 + ri + 1) * PH_ + x0 + ci * 16 + lm + 1) * 64;
      bf16 t[4];
#pragma unroll
      for (int r = 0; r < 4; ++r) {
        float v = acc[nf][0][r] + bias[ocb + r];
        v = v > 0.f ? v : 0.1f * v;
        t[r] = __float2bfloat16(v);
      }
      *(uint2*)(ob + pix + ocb) = *(const uint2*)t;
    }
  } else {
#pragma unroll
    for (int nf = 0; nf < 4; ++nf) {
      int ri = nf >> 1, ci = nf & 1;
      int y = y0 + ri, x = x0 + ci * 16 + lm;
#pragma unroll
      for (int oh = 0; oh < OCH; ++oh) {
        int oc0 = w * (OCH * 16) + oh * 16 + r4;
#pragma unroll
        for (int r = 0; r < 4; ++r) {
          int oc = oc0 + r;
          if (oc < 216) {
            float v = acc[nf][oh][r] + bias[oc];
            if (oc >= 144) v = 1.f / (1.f + __expf(-v));
            g_CO[((size_t)(b * 216 + oc) * H_ + y) * W_ + x] = v;
          }
        }
      }
    }
  }
}

// ---------------- fused modulated deformable conv ----------------
// grid: (800, B). block 256. 32 px x 64 oc. x is padded NHWC bf16.
#define LO16(u) __uint_as_float((u) << 16)
#define HI16(u) __uint_as_float((u) & 0xffff0000u)

__global__ __launch_bounds__(256)
void dcn_k(int x_id, int wd_off, const float* __restrict__ bias,
           float* __restrict__ outp, int xt_out_id)
{
  const bf16* xT = pbuf(x_id);
  const bf16* WD = g_WD + wd_off;               // [18][4][64][8]
  __shared__ __align__(16) bf16 vS[32 * 584];
  int tid = threadIdx.x;
  int b = blockIdx.y;
  int h = blockIdx.x / 5;
  int w0 = (blockIdx.x % 5) * 32;
  const bf16* xb = xT + (size_t)b * PHW_ * 64;

  // ---- phase A: hoisted co loads, then bf16 gathers ----
  const float* cob = g_CO + ((size_t)b * 216 * HW_) + h * W_ + w0;
  float oy[9], ox[9], mk[9];
#pragma unroll
  for (int t = 0; t < 9; ++t) {
    int idx = t * 256 + tid;
    int gk = idx >> 5, p = idx & 31;
    oy[t] = cob[(gk * 2) * HW_ + p];
    ox[t] = cob[(gk * 2 + 1) * HW_ + p];
    mk[t] = cob[(144 + gk) * HW_ + p];   // pre-sigmoided
  }
#pragma unroll
  for (int t = 0; t < 9; ++t) {
    int idx = t * 256 + tid;
    int gk = idx >> 5, p = idx & 31;
    int g = gk / 9, kk = gk - g * 9;
    float pyf = oy[t] + (float)(kk / 3 - 1 + h);
    float pxf = ox[t] + (float)(kk % 3 - 1 + w0 + p);
    float y0f = floorf(pyf), x0f = floorf(pxf);
    float ly = pyf - y0f, lx = pxf - x0f;
    int iy0 = (int)y0f, ix0 = (int)x0f;
    int iy1 = iy0 + 1, ix1 = ix0 + 1;
    float mask = mk[t];
    float w00 = (1.f - ly) * (1.f - lx) * mask;
    float w01 = (1.f - ly) * lx * mask;
    float w10 = ly * (1.f - lx) * mask;
    float w11 = ly * lx * mask;
    if (iy0 < 0 || iy0 >= H_) { w00 = 0.f; w01 = 0.f; }
    if (iy1 < 0 || iy1 >= H_) { w10 = 0.f; w11 = 0.f; }
    if (ix0 < 0 || ix0 >= W_) { w00 = 0.f; w10 = 0.f; }
    if (ix1 < 0 || ix1 >= W_) { w01 = 0.f; w11 = 0.f; }
    int cy0 = min(max(iy0, 0), H_ - 1), cy1 = min(max(iy1, 0), H_ - 1);
    int cx0 = min(max(ix0, 0), W_ - 1), cx1 = min(max(ix1, 0), W_ - 1);
    int gb = g * 8;
    uint4 u00 = *(const uint4*)(xb + ((size_t)(cy0 + 1) * PH_ + cx0 + 1) * 64 + gb);
    uint4 u01 = *(const uint4*)(xb + ((size_t)(cy0 + 1) * PH_ + cx1 + 1) * 64 + gb);
    uint4 u10 = *(const uint4*)(xb + ((size_t)(cy1 + 1) * PH_ + cx0 + 1) * 64 + gb);
    uint4 u11 = *(const uint4*)(xb + ((size_t)(cy1 + 1) * PH_ + cx1 + 1) * 64 + gb);
    bf16 tmp[8];
#define LERP2(ci, A, Bq, Cq, Dq) { \
    float vlo = w00 * LO16(A) + w01 * LO16(Bq) + w10 * LO16(Cq) + w11 * LO16(Dq); \
    float vhi = w00 * HI16(A) + w01 * HI16(Bq) + w10 * HI16(Cq) + w11 * HI16(Dq); \
    tmp[2*(ci)] = __float2bfloat16(vlo); tmp[2*(ci)+1] = __float2bfloat16(vhi); }
    LERP2(0, u00.x, u01.x, u10.x, u11.x);
    LERP2(1, u00.y, u01.y, u10.y, u11.y);
    LERP2(2, u00.z, u01.z, u10.z, u11.z);
    LERP2(3, u00.w, u01.w, u10.w, u11.w);
#undef LERP2
    *(uint4*)&vS[p * 584 + g * 72 + kk * 8] = *(const uint4*)tmp;
  }
  __syncthreads();

  // ---- phase B: MFMA ----
  int w = tid >> 6;
  int L = tid & 63;
  int lm = L & 15;
  int k0 = (L >> 4) * 8;
  int mt = w & 1;
  int nb2 = (w >> 1) * 2;
  f32x4 acc2[2];
  acc2[0] = (f32x4)0.f; acc2[1] = (f32x4)0.f;
#pragma unroll 3
  for (int kc = 0; kc < 18; ++kc) {
    bf16x8 a = *(const bf16x8*)&vS[(mt * 16 + lm) * 584 + kc * 32 + k0];
#pragma unroll
    for (int i = 0; i < 2; ++i) {
      bf16x8 bw = *(const bf16x8*)(WD + ((kc * 4 + nb2 + i) * 64 + L) * 8);
      acc2[i] = __builtin_amdgcn_mfma_f32_16x16x32_bf16(a, bw, acc2[i], 0, 0, 0);
    }
  }
  __syncthreads();

  // ---- epilogue through LDS ----
  float* outS = (float*)vS;          // [64 oc][33]
#pragma unroll
  for (int i = 0; i < 2; ++i)
#pragma unroll
    for (int r = 0; r < 4; ++r) {
      int oc = (nb2 + i) * 16 + lm;
      int px = mt * 16 + (L >> 4) * 4 + r;
      outS[oc * 33 + px] = acc2[i][r];
    }
  __syncthreads();
  if (outp) {
    for (int i = tid; i < 2048; i += 256) {
      int oc = i >> 5, p2 = i & 31;
      float v = outS[oc * 33 + p2] + bias[oc];
      v = v > 0.f ? v : 0.1f * v;
      outp[((size_t)(b * 64 + oc) * H_ + h) * W_ + w0 + p2] = v;
    }
  }
  if (xt_out_id) {
    bf16* xt = pbuf(xt_out_id) + (size_t)b * PHW_ * 64;
    for (int i = tid; i < 2048; i += 256) {
      int p2 = i >> 6, c = i & 63;
      float v = outS[c * 33 + p2] + bias[c];
      v = v > 0.f ? v : 0.1f * v;
      xt[((size_t)(h + 1) * PH_ + w0 + p2 + 1) * 64 + c] = __float2bfloat16(v);
    }
  }
}

extern "C" void kernel_launch(void* const* d_in, const int* in_sizes, int n_in,
                              void* d_out, int out_size, void* d_ws, size_t ws_size,
                              hipStream_t stream) {
  (void)in_sizes; (void)n_in; (void)out_size; (void)d_ws; (void)ws_size;
  const float* nbr    = (const float*)d_in[0];
  const float* ref    = (const float*)d_in[1];
  const float* w_off1 = (const float*)d_in[2];
  const float* b_off1 = (const float*)d_in[3];
  const float* w_off2 = (const float*)d_in[4];
  const float* b_off2 = (const float*)d_in[5];
  const float* w_co   = (const float*)d_in[6];
  const float* b_co   = (const float*)d_in[7];
  const float* w_dcn  = (const float*)d_in[8];
  const float* b_dcn  = (const float*)d_in[9];
  const float* w_coff1= (const float*)d_in[10];
  const float* b_coff1= (const float*)d_in[11];
  const float* w_coff2= (const float*)d_in[12];
  const float* b_coff2= (const float*)d_in[13];
  const float* w_cco  = (const float*)d_in[14];
  const float* b_cco  = (const float*)d_in[15];
  const float* w_cdcn = (const float*)d_in[16];
  const float* b_cdcn = (const float*)d_in[17];

  prep_wfrag<<<288, 256, 0, stream>>>(w_off1, 0, 64, 128, 1, 4);
  prep_wfrag<<<144, 256, 0, stream>>>(w_off2, 73728, 64, 64, 1, 4);
  prep_wfrag<<<576, 256, 0, stream>>>(w_co, 110592, 216, 64, 1, 16);
  prep_wfrag<<<288, 256, 0, stream>>>(w_coff1, 258048, 64, 128, 1, 4);
  prep_wfrag<<<144, 256, 0, stream>>>(w_coff2, 331776, 64, 64, 1, 4);
  prep_wfrag<<<576, 256, 0, stream>>>(w_cco, 368640, 216, 64, 1, 16);
  prep_wdcnfrag<<<144, 256, 0, stream>>>(w_dcn, 0);
  prep_wdcnfrag<<<144, 256, 0, stream>>>(w_cdcn, 36864);

  dim3 blk(256);
  float* out = (float*)d_out;
  // padded NHWC bf16 inputs
  nchw2nhwc_pad<<<dim3(160, 4), blk, 0, stream>>>(nbr, 1);
  nchw2nhwc_pad<<<dim3(160, 4), blk, 0, stream>>>(ref, 2);
  // A1 = lrelu(conv(cat(nbr,ref))); A2 = lrelu(conv(A1)); CO = conv(A2)
  conv_nhwc<4,1,0><<<dim3(400, 4), blk, 0, stream>>>(1, 2, 2, 0, b_off1, 3);
  conv_nhwc<2,1,0><<<dim3(400, 4), blk, 0, stream>>>(3, 3, 2, 73728, b_off2, 4);
  conv_nhwc<2,4,1><<<dim3(400, 4), blk, 0, stream>>>(4, 4, 2, 110592, b_co, 0);
  // F1 = lrelu(dcn(Xnbr, CO))  (padded NHWC bf16 only)
  dcn_k<<<dim3(800, 4), blk, 0, stream>>>(1, 0, b_dcn, nullptr, 5);
  // cascade
  conv_nhwc<4,1,0><<<dim3(400, 4), blk, 0, stream>>>(5, 2, 2, 258048, b_coff1, 3);
  conv_nhwc<2,1,0><<<dim3(400, 4), blk, 0, stream>>>(3, 3, 2, 331776, b_coff2, 4);
  conv_nhwc<2,4,1><<<dim3(400, 4), blk, 0, stream>>>(4, 4, 2, 368640, b_cco, 0);
  // out = lrelu(dcn(F1, CO))
  dcn_k<<<dim3(800, 4), blk, 0, stream>>>(5, 36864, b_cdcn, out, 0);
}

// Round 3
// 772.718 us; speedup vs baseline: 1.0547x; 1.0547x over previous
//
#include <hip/hip_runtime.h>
#include <hip/hip_bf16.h>
#include <stdint.h>

#define B_ 4
#define H_ 160
#define W_ 160
#define HW_ 25600
#define PH_ 162
#define PHW_ 26244   // 162*162

typedef __hip_bfloat16 bf16;
typedef __attribute__((ext_vector_type(8))) short bf16x8;
typedef __attribute__((ext_vector_type(4))) float f32x4;

// ---------------- static workspace (module .bss) ----------------
// Padded NHWC bf16 activation buffers: [B][162][162][64], borders stay zero.
__device__ float g_CO[22118400];              // (4,216,160,160) NCHW f32; mask pre-sigmoided
__device__ __align__(16) bf16 g_P1[6718464];  // Xnbr  (padded NHWC bf16 of nbr)
__device__ __align__(16) bf16 g_P2[6718464];  // Xref
__device__ __align__(16) bf16 g_P3[6718464];  // A1
__device__ __align__(16) bf16 g_P4[6718464];  // A2
__device__ __align__(16) bf16 g_P5[6718464];  // F1 (dcn1 out / dcn2 x / coff1 in)
__device__ __align__(16) bf16 g_WB[516096];   // conv weights, fragment order
__device__ __align__(16) bf16 g_WD[73728];    // 2 x dcn weights, frag, K-permuted

__device__ __forceinline__ bf16* pbuf(int id) {
  if (id == 1) return g_P1;
  if (id == 2) return g_P2;
  if (id == 3) return g_P3;
  if (id == 4) return g_P4;
  return g_P5;
}

// XCD-aware bijective swizzle (grid multiple of 8).
__device__ __forceinline__ int xcdswz(int bx, int q) {
  return (bx & 7) * q + (bx >> 3);
}

// ---------------- weight prep: conv fragment order ----------------
// layout [cc][tap][nt(NTPB)][lane(64)][j(8)]
__global__ void prep_wfrag(const float* __restrict__ src, int off,
                           int OC, int CIN, int NB, int NTPB) {
  int i = blockIdx.x * 256 + threadIdx.x;
  int CC = CIN >> 5;
  int total = NB * CC * 9 * NTPB * 512;
  if (i >= total) return;
  int j = i & 7;
  int t = i >> 3;
  int lane = t & 63; t >>= 6;
  int nt = t % NTPB; t /= NTPB;
  int tap = t % 9; t /= 9;
  int cc = t % CC; int nb = t / CC;
  int oc = nb * (NTPB * 16) + nt * 16 + (lane & 15);
  int ci = cc * 32 + (lane >> 4) * 8 + j;
  float v = (oc < OC) ? src[(oc * CIN + ci) * 9 + tap] : 0.f;
  g_WB[off + i] = __float2bfloat16(v);
}

// dcn weights -> frag order with K-permutation k' = g*72 + kk*8 + c
__global__ void prep_wdcnfrag(const float* __restrict__ src, int off) {
  int i = blockIdx.x * 256 + threadIdx.x;
  if (i >= 36864) return;
  int j = i & 7;
  int t = i >> 3;
  int lane = t & 63; t >>= 6;
  int nt = t & 3; int kc = t >> 2;
  int kp = kc * 32 + (lane >> 4) * 8 + j;
  int oc = nt * 16 + (lane & 15);
  int g = kp / 72, r = kp - g * 72;
  int kk = r >> 3, c = r & 7;
  g_WD[off + i] = __float2bfloat16(src[oc * 576 + g * 72 + c * 9 + kk]);
}

// ---------------- NCHW f32 -> padded NHWC bf16 (64 ch) ----------------
// grid (160, B): one image row per block.
__global__ __launch_bounds__(256)
void nchw2nhwc_pad(const float* __restrict__ in, int out_id) {
  __shared__ float T[64][161];
  int tid = threadIdx.x;
  int y = blockIdx.x, b = blockIdx.y;
#pragma unroll
  for (int it = 0; it < 10; ++it) {
    int i = it * 256 + tid;                 // 2560 float4 loads
    int c = i / 40, xq = i - c * 40;
    float4 v = *(const float4*)&in[((size_t)(b * 64 + c) * H_ + y) * W_ + xq * 4];
    T[c][xq * 4 + 0] = v.x; T[c][xq * 4 + 1] = v.y;
    T[c][xq * 4 + 2] = v.z; T[c][xq * 4 + 3] = v.w;
  }
  __syncthreads();
  bf16* ob = pbuf(out_id) + ((size_t)b * PHW_ + (size_t)(y + 1) * PH_ + 1) * 64;
#pragma unroll
  for (int it = 0; it < 5; ++it) {
    int i = it * 256 + tid;                 // 1280 8-ch chunks
    int px = i >> 3, c0 = (i & 7) * 8;
    bf16 t[8];
#pragma unroll
    for (int j = 0; j < 8; ++j) t[j] = __float2bfloat16(T[c0 + j][px]);
    *(uint4*)(ob + (size_t)px * 64 + c0) = *(const uint4*)t;
  }
}

// ---------------- implicit-GEMM conv3x3 (NHWC bf16), LDS-transposed epilogue ----------------
// Block: 2 rows x 32 px, 4 waves. MFMA A=weights -> D rows = oc, D cols = px.
// Epilogue transposes through LDS so every global store instruction writes
// complete 128B cache lines (fixes 14x write amplification seen in R2).
// MODE 0: lrelu -> padded NHWC bf16.  MODE 1: CO out NCHW f32, sigmoid oc>=144.
template<int CC, int OCH, int MODE>
__global__ __launch_bounds__(256, 4)
void conv_nhwc(int in1_id, int in2_id, int ccsplit, int woff,
               const float* __restrict__ bias, int out_id)
{
  constexpr int NTPB = 4 * OCH;
  constexpr int LDS_BYTES = (MODE == 0) ? 64 * 66 * 2 : 216 * 34 * 4;
  __shared__ __align__(16) char SH[LDS_BYTES];

  int tid = threadIdx.x;
  int w = tid >> 6, L = tid & 63, lm = L & 15;
  int k0 = (L >> 4) * 8;
  int r4 = (L >> 4) * 4;
  int bx = xcdswz(blockIdx.x, 50);
  int b = blockIdx.y;
  int y0 = (bx / 5) * 2, x0 = (bx % 5) * 32;
  const bf16* s1 = pbuf(in1_id) + (size_t)b * PHW_ * 64;
  const bf16* s2 = pbuf(in2_id) + (size_t)b * PHW_ * 64;
  const bf16* wl = g_WB + woff + L * 8;

  f32x4 acc[4][OCH];
#pragma unroll
  for (int nf = 0; nf < 4; ++nf)
#pragma unroll
    for (int oh = 0; oh < OCH; ++oh) acc[nf][oh] = (f32x4)0.f;

#pragma unroll
  for (int cc = 0; cc < CC; ++cc) {
    const bf16* sb = (cc < ccsplit) ? (s1 + cc * 32) : (s2 + (cc - ccsplit) * 32);
#pragma unroll
    for (int tap = 0; tap < 9; ++tap) {
      const int dy = tap / 3, dx = tap - dy * 3;
      const int ks = cc * 9 + tap;
      bf16x8 af[4];
#pragma unroll
      for (int nf = 0; nf < 4; ++nf) {
        int ri = nf >> 1, ci = nf & 1;
        af[nf] = *(const bf16x8*)(sb +
            (size_t)((y0 + ri + dy) * PH_ + x0 + ci * 16 + dx + lm) * 64 + k0);
      }
#pragma unroll
      for (int oh = 0; oh < OCH; ++oh) {
        bf16x8 wf = *(const bf16x8*)(wl + (size_t)(ks * NTPB + w * OCH + oh) * 512);
#pragma unroll
        for (int nf = 0; nf < 4; ++nf)
          acc[nf][oh] = __builtin_amdgcn_mfma_f32_16x16x32_bf16(wf, af[nf], acc[nf][oh], 0, 0, 0);
      }
    }
  }

  if (MODE == 0) {
    // ---- transpose 64px x 64ch through LDS; full-line uint4 stores ----
    bf16* TS = (bf16*)SH;               // [64 px][66]
    int ocb = w * 16 + r4;
#pragma unroll
    for (int nf = 0; nf < 4; ++nf) {
      int ri = nf >> 1, ci = nf & 1;
      int p = ri * 32 + ci * 16 + lm;
      bf16 t[4];
#pragma unroll
      for (int r = 0; r < 4; ++r) {
        float v = acc[nf][0][r] + bias[ocb + r];
        v = v > 0.f ? v : 0.1f * v;
        t[r] = __float2bfloat16(v);
      }
      *(uint2*)&TS[p * 66 + ocb] = *(const uint2*)t;
    }
    __syncthreads();
    bf16* ob = pbuf(out_id) + ((size_t)b * PHW_ + (size_t)(y0 + 1) * PH_ + x0 + 1) * 64;
#pragma unroll
    for (int it = 0; it < 2; ++it) {
      int i = it * 256 + tid;
      int p = i >> 3, c0 = (i & 7) * 8;
      int ri = p >> 5, xo = p & 31;
      *(uint4*)(ob + ((size_t)ri * PH_ + xo) * 64 + c0) = *(const uint4*)&TS[p * 66 + c0];
    }
  } else {
    // ---- CO: two row-passes through LDS [216][34]; full-line f32 stores ----
    float* TS = (float*)SH;
#pragma unroll
    for (int ri = 0; ri < 2; ++ri) {
      __syncthreads();
#pragma unroll
      for (int ci = 0; ci < 2; ++ci) {
        int nf = ri * 2 + ci;
#pragma unroll
        for (int oh = 0; oh < OCH; ++oh) {
#pragma unroll
          for (int r = 0; r < 4; ++r) {
            int oc = w * (OCH * 16) + oh * 16 + r4 + r;
            if (oc < 216) {
              float v = acc[nf][oh][r] + bias[oc];
              if (oc >= 144) v = 1.f / (1.f + __expf(-v));
              TS[oc * 34 + ci * 16 + lm] = v;
            }
          }
        }
      }
      __syncthreads();
      float* cb2 = g_CO + ((size_t)b * 216 * HW_) + (size_t)(y0 + ri) * W_ + x0;
      for (int i = tid; i < 6912; i += 256) {
        int oc = i >> 5, x = i & 31;
        cb2[(size_t)oc * HW_ + x] = TS[oc * 34 + x];
      }
    }
  }
}

// ---------------- fused modulated deformable conv ----------------
// grid: (800, B). block 256. 32 px x 64 oc. x is padded NHWC bf16.
#define LO16(u) __uint_as_float((u) << 16)
#define HI16(u) __uint_as_float((u) & 0xffff0000u)

__global__ __launch_bounds__(256)
void dcn_k(int x_id, int wd_off, const float* __restrict__ bias,
           float* __restrict__ outp, int xt_out_id)
{
  const bf16* xT = pbuf(x_id);
  const bf16* WD = g_WD + wd_off;               // [18][4][64][8]
  __shared__ __align__(16) bf16 vS[32 * 584];
  int tid = threadIdx.x;
  int b = blockIdx.y;
  int bx = xcdswz(blockIdx.x, 100);
  int h = bx / 5;
  int w0 = (bx % 5) * 32;
  const bf16* xb = xT + (size_t)b * PHW_ * 64;

  // ---- phase A: hoisted co loads, then bf16 gathers ----
  const float* cob = g_CO + ((size_t)b * 216 * HW_) + h * W_ + w0;
  float oy[9], ox[9], mk[9];
#pragma unroll
  for (int t = 0; t < 9; ++t) {
    int idx = t * 256 + tid;
    int gk = idx >> 5, p = idx & 31;
    oy[t] = cob[(gk * 2) * HW_ + p];
    ox[t] = cob[(gk * 2 + 1) * HW_ + p];
    mk[t] = cob[(144 + gk) * HW_ + p];   // pre-sigmoided
  }
#pragma unroll
  for (int t = 0; t < 9; ++t) {
    int idx = t * 256 + tid;
    int gk = idx >> 5, p = idx & 31;
    int g = gk / 9, kk = gk - g * 9;
    float pyf = oy[t] + (float)(kk / 3 - 1 + h);
    float pxf = ox[t] + (float)(kk % 3 - 1 + w0 + p);
    float y0f = floorf(pyf), x0f = floorf(pxf);
    float ly = pyf - y0f, lx = pxf - x0f;
    int iy0 = (int)y0f, ix0 = (int)x0f;
    int iy1 = iy0 + 1, ix1 = ix0 + 1;
    float mask = mk[t];
    float w00 = (1.f - ly) * (1.f - lx) * mask;
    float w01 = (1.f - ly) * lx * mask;
    float w10 = ly * (1.f - lx) * mask;
    float w11 = ly * lx * mask;
    if (iy0 < 0 || iy0 >= H_) { w00 = 0.f; w01 = 0.f; }
    if (iy1 < 0 || iy1 >= H_) { w10 = 0.f; w11 = 0.f; }
    if (ix0 < 0 || ix0 >= W_) { w00 = 0.f; w10 = 0.f; }
    if (ix1 < 0 || ix1 >= W_) { w01 = 0.f; w11 = 0.f; }
    int cy0 = min(max(iy0, 0), H_ - 1), cy1 = min(max(iy1, 0), H_ - 1);
    int cx0 = min(max(ix0, 0), W_ - 1), cx1 = min(max(ix1, 0), W_ - 1);
    int gb = g * 8;
    uint4 u00 = *(const uint4*)(xb + ((size_t)(cy0 + 1) * PH_ + cx0 + 1) * 64 + gb);
    uint4 u01 = *(const uint4*)(xb + ((size_t)(cy0 + 1) * PH_ + cx1 + 1) * 64 + gb);
    uint4 u10 = *(const uint4*)(xb + ((size_t)(cy1 + 1) * PH_ + cx0 + 1) * 64 + gb);
    uint4 u11 = *(const uint4*)(xb + ((size_t)(cy1 + 1) * PH_ + cx1 + 1) * 64 + gb);
    bf16 tmp[8];
#define LERP2(ci, A, Bq, Cq, Dq) { \
    float vlo = w00 * LO16(A) + w01 * LO16(Bq) + w10 * LO16(Cq) + w11 * LO16(Dq); \
    float vhi = w00 * HI16(A) + w01 * HI16(Bq) + w10 * HI16(Cq) + w11 * HI16(Dq); \
    tmp[2*(ci)] = __float2bfloat16(vlo); tmp[2*(ci)+1] = __float2bfloat16(vhi); }
    LERP2(0, u00.x, u01.x, u10.x, u11.x);
    LERP2(1, u00.y, u01.y, u10.y, u11.y);
    LERP2(2, u00.z, u01.z, u10.z, u11.z);
    LERP2(3, u00.w, u01.w, u10.w, u11.w);
#undef LERP2
    *(uint4*)&vS[p * 584 + g * 72 + kk * 8] = *(const uint4*)tmp;
  }
  __syncthreads();

  // ---- phase B: MFMA ----
  int w = tid >> 6;
  int L = tid & 63;
  int lm = L & 15;
  int k0 = (L >> 4) * 8;
  int mt = w & 1;
  int nb2 = (w >> 1) * 2;
  f32x4 acc2[2];
  acc2[0] = (f32x4)0.f; acc2[1] = (f32x4)0.f;
#pragma unroll 3
  for (int kc = 0; kc < 18; ++kc) {
    bf16x8 a = *(const bf16x8*)&vS[(mt * 16 + lm) * 584 + kc * 32 + k0];
#pragma unroll
    for (int i = 0; i < 2; ++i) {
      bf16x8 bw = *(const bf16x8*)(WD + ((kc * 4 + nb2 + i) * 64 + L) * 8);
      acc2[i] = __builtin_amdgcn_mfma_f32_16x16x32_bf16(a, bw, acc2[i], 0, 0, 0);
    }
  }
  __syncthreads();

  // ---- epilogue through LDS (stores are already full-line) ----
  float* outS = (float*)vS;          // [64 oc][33]
#pragma unroll
  for (int i = 0; i < 2; ++i)
#pragma unroll
    for (int r = 0; r < 4; ++r) {
      int oc = (nb2 + i) * 16 + lm;
      int px = mt * 16 + (L >> 4) * 4 + r;
      outS[oc * 33 + px] = acc2[i][r];
    }
  __syncthreads();
  if (outp) {
    for (int i = tid; i < 2048; i += 256) {
      int oc = i >> 5, p2 = i & 31;
      float v = outS[oc * 33 + p2] + bias[oc];
      v = v > 0.f ? v : 0.1f * v;
      outp[((size_t)(b * 64 + oc) * H_ + h) * W_ + w0 + p2] = v;
    }
  }
  if (xt_out_id) {
    bf16* xt = pbuf(xt_out_id) + (size_t)b * PHW_ * 64;
    for (int i = tid; i < 2048; i += 256) {
      int p2 = i >> 6, c = i & 63;
      float v = outS[c * 33 + p2] + bias[c];
      v = v > 0.f ? v : 0.1f * v;
      xt[((size_t)(h + 1) * PH_ + w0 + p2 + 1) * 64 + c] = __float2bfloat16(v);
    }
  }
}

extern "C" void kernel_launch(void* const* d_in, const int* in_sizes, int n_in,
                              void* d_out, int out_size, void* d_ws, size_t ws_size,
                              hipStream_t stream) {
  (void)in_sizes; (void)n_in; (void)out_size; (void)d_ws; (void)ws_size;
  const float* nbr    = (const float*)d_in[0];
  const float* ref    = (const float*)d_in[1];
  const float* w_off1 = (const float*)d_in[2];
  const float* b_off1 = (const float*)d_in[3];
  const float* w_off2 = (const float*)d_in[4];
  const float* b_off2 = (const float*)d_in[5];
  const float* w_co   = (const float*)d_in[6];
  const float* b_co   = (const float*)d_in[7];
  const float* w_dcn  = (const float*)d_in[8];
  const float* b_dcn  = (const float*)d_in[9];
  const float* w_coff1= (const float*)d_in[10];
  const float* b_coff1= (const float*)d_in[11];
  const float* w_coff2= (const float*)d_in[12];
  const float* b_coff2= (const float*)d_in[13];
  const float* w_cco  = (const float*)d_in[14];
  const float* b_cco  = (const float*)d_in[15];
  const float* w_cdcn = (const float*)d_in[16];
  const float* b_cdcn = (const float*)d_in[17];

  prep_wfrag<<<288, 256, 0, stream>>>(w_off1, 0, 64, 128, 1, 4);
  prep_wfrag<<<144, 256, 0, stream>>>(w_off2, 73728, 64, 64, 1, 4);
  prep_wfrag<<<576, 256, 0, stream>>>(w_co, 110592, 216, 64, 1, 16);
  prep_wfrag<<<288, 256, 0, stream>>>(w_coff1, 258048, 64, 128, 1, 4);
  prep_wfrag<<<144, 256, 0, stream>>>(w_coff2, 331776, 64, 64, 1, 4);
  prep_wfrag<<<576, 256, 0, stream>>>(w_cco, 368640, 216, 64, 1, 16);
  prep_wdcnfrag<<<144, 256, 0, stream>>>(w_dcn, 0);
  prep_wdcnfrag<<<144, 256, 0, stream>>>(w_cdcn, 36864);

  dim3 blk(256);
  float* out = (float*)d_out;
  // padded NHWC bf16 inputs
  nchw2nhwc_pad<<<dim3(160, 4), blk, 0, stream>>>(nbr, 1);
  nchw2nhwc_pad<<<dim3(160, 4), blk, 0, stream>>>(ref, 2);
  // A1 = lrelu(conv(cat(nbr,ref))); A2 = lrelu(conv(A1)); CO = conv(A2)
  conv_nhwc<4,1,0><<<dim3(400, 4), blk, 0, stream>>>(1, 2, 2, 0, b_off1, 3);
  conv_nhwc<2,1,0><<<dim3(400, 4), blk, 0, stream>>>(3, 3, 2, 73728, b_off2, 4);
  conv_nhwc<2,4,1><<<dim3(400, 4), blk, 0, stream>>>(4, 4, 2, 110592, b_co, 0);
  // F1 = lrelu(dcn(Xnbr, CO))  (padded NHWC bf16 only)
  dcn_k<<<dim3(800, 4), blk, 0, stream>>>(1, 0, b_dcn, nullptr, 5);
  // cascade
  conv_nhwc<4,1,0><<<dim3(400, 4), blk, 0, stream>>>(5, 2, 2, 258048, b_coff1, 3);
  conv_nhwc<2,1,0><<<dim3(400, 4), blk, 0, stream>>>(3, 3, 2, 331776, b_coff2, 4);
  conv_nhwc<2,4,1><<<dim3(400, 4), blk, 0, stream>>>(4, 4, 2, 368640, b_cco, 0);
  // out = lrelu(dcn(F1, CO))
  dcn_k<<<dim3(800, 4), blk, 0, stream>>>(6 - 1, 36864, b_cdcn, out, 0);
}

// Round 4
// 735.078 us; speedup vs baseline: 1.1087x; 1.0512x over previous
//
#include <hip/hip_runtime.h>
#include <hip/hip_bf16.h>
#include <stdint.h>

#define B_ 4
#define H_ 160
#define W_ 160
#define HW_ 25600
#define PH_ 162
#define PHW_ 26244   // 162*162

typedef __hip_bfloat16 bf16;
typedef __attribute__((ext_vector_type(8))) short bf16x8;
typedef __attribute__((ext_vector_type(4))) float f32x4;

// ---------------- static workspace (module .bss) ----------------
// Padded NHWC bf16 activation buffers: [B][162][162][64], borders stay zero.
// g_CO eliminated: the 216-ch offset conv is fused into dcn_k (saves ~354 MB
// of fabric traffic per iteration at the measured ~1.8 TB/s pattern ceiling).
__device__ __align__(16) bf16 g_P1[6718464];  // Xnbr  (padded NHWC bf16 of nbr)
__device__ __align__(16) bf16 g_P2[6718464];  // Xref
__device__ __align__(16) bf16 g_P3[6718464];  // A1
__device__ __align__(16) bf16 g_P4[6718464];  // A2
__device__ __align__(16) bf16 g_P5[6718464];  // F1 (dcn1 out / dcn2 x / coff1 in)
__device__ __align__(16) bf16 g_WB[516096];   // conv weights, fragment order
__device__ __align__(16) bf16 g_WD[73728];    // 2 x dcn weights, frag, K-permuted

__device__ __forceinline__ bf16* pbuf(int id) {
  if (id == 1) return g_P1;
  if (id == 2) return g_P2;
  if (id == 3) return g_P3;
  if (id == 4) return g_P4;
  return g_P5;
}

// XCD-aware bijective swizzle (grid multiple of 8).
__device__ __forceinline__ int xcdswz(int bx, int q) {
  return (bx & 7) * q + (bx >> 3);
}

// ---------------- weight prep: conv fragment order ----------------
// layout [cc][tap][nt(NTPB)][lane(64)][j(8)]
__global__ void prep_wfrag(const float* __restrict__ src, int off,
                           int OC, int CIN, int NB, int NTPB) {
  int i = blockIdx.x * 256 + threadIdx.x;
  int CC = CIN >> 5;
  int total = NB * CC * 9 * NTPB * 512;
  if (i >= total) return;
  int j = i & 7;
  int t = i >> 3;
  int lane = t & 63; t >>= 6;
  int nt = t % NTPB; t /= NTPB;
  int tap = t % 9; t /= 9;
  int cc = t % CC; int nb = t / CC;
  int oc = nb * (NTPB * 16) + nt * 16 + (lane & 15);
  int ci = cc * 32 + (lane >> 4) * 8 + j;
  float v = (oc < OC) ? src[(oc * CIN + ci) * 9 + tap] : 0.f;
  g_WB[off + i] = __float2bfloat16(v);
}

// dcn weights -> frag order with K-permutation k' = g*72 + kk*8 + c
__global__ void prep_wdcnfrag(const float* __restrict__ src, int off) {
  int i = blockIdx.x * 256 + threadIdx.x;
  if (i >= 36864) return;
  int j = i & 7;
  int t = i >> 3;
  int lane = t & 63; t >>= 6;
  int nt = t & 3; int kc = t >> 2;
  int kp = kc * 32 + (lane >> 4) * 8 + j;
  int oc = nt * 16 + (lane & 15);
  int g = kp / 72, r = kp - g * 72;
  int kk = r >> 3, c = r & 7;
  g_WD[off + i] = __float2bfloat16(src[oc * 576 + g * 72 + c * 9 + kk]);
}

// ---------------- NCHW f32 -> padded NHWC bf16 (64 ch) ----------------
// grid (160, B): one image row per block.
__global__ __launch_bounds__(256)
void nchw2nhwc_pad(const float* __restrict__ in, int out_id) {
  __shared__ float T[64][161];
  int tid = threadIdx.x;
  int y = blockIdx.x, b = blockIdx.y;
#pragma unroll
  for (int it = 0; it < 10; ++it) {
    int i = it * 256 + tid;                 // 2560 float4 loads
    int c = i / 40, xq = i - c * 40;
    float4 v = *(const float4*)&in[((size_t)(b * 64 + c) * H_ + y) * W_ + xq * 4];
    T[c][xq * 4 + 0] = v.x; T[c][xq * 4 + 1] = v.y;
    T[c][xq * 4 + 2] = v.z; T[c][xq * 4 + 3] = v.w;
  }
  __syncthreads();
  bf16* ob = pbuf(out_id) + ((size_t)b * PHW_ + (size_t)(y + 1) * PH_ + 1) * 64;
#pragma unroll
  for (int it = 0; it < 5; ++it) {
    int i = it * 256 + tid;                 // 1280 8-ch chunks
    int px = i >> 3, c0 = (i & 7) * 8;
    bf16 t[8];
#pragma unroll
    for (int j = 0; j < 8; ++j) t[j] = __float2bfloat16(T[c0 + j][px]);
    *(uint4*)(ob + (size_t)px * 64 + c0) = *(const uint4*)t;
  }
}

// ---------------- implicit-GEMM conv3x3 (NHWC bf16, 64 oc), lrelu ----------------
// Block: 2 rows x 32 px, 4 waves, wave w owns oc [w*16, w*16+16).
// MFMA A=weights -> D rows = oc, D cols = px. LDS-transposed epilogue gives
// full-128B-line NHWC stores.
template<int CC>
__global__ __launch_bounds__(256, 4)
void conv_nhwc(int in1_id, int in2_id, int ccsplit, int woff,
               const float* __restrict__ bias, int out_id)
{
  __shared__ __align__(16) bf16 TS[64 * 66];   // [64 px][66]

  int tid = threadIdx.x;
  int w = tid >> 6, L = tid & 63, lm = L & 15;
  int k0 = (L >> 4) * 8;
  int r4 = (L >> 4) * 4;
  int bx = xcdswz(blockIdx.x, 50);
  int b = blockIdx.y;
  int y0 = (bx / 5) * 2, x0 = (bx % 5) * 32;
  const bf16* s1 = pbuf(in1_id) + (size_t)b * PHW_ * 64;
  const bf16* s2 = pbuf(in2_id) + (size_t)b * PHW_ * 64;
  const bf16* wl = g_WB + woff + L * 8;

  f32x4 acc[4];
#pragma unroll
  for (int nf = 0; nf < 4; ++nf) acc[nf] = (f32x4)0.f;

#pragma unroll
  for (int cc = 0; cc < CC; ++cc) {
    const bf16* sb = (cc < ccsplit) ? (s1 + cc * 32) : (s2 + (cc - ccsplit) * 32);
#pragma unroll
    for (int tap = 0; tap < 9; ++tap) {
      const int dy = tap / 3, dx = tap - dy * 3;
      const int ks = cc * 9 + tap;
      bf16x8 wf = *(const bf16x8*)(wl + (size_t)(ks * 4 + w) * 512);
#pragma unroll
      for (int nf = 0; nf < 4; ++nf) {
        int ri = nf >> 1, ci = nf & 1;
        bf16x8 af = *(const bf16x8*)(sb +
            (size_t)((y0 + ri + dy) * PH_ + x0 + ci * 16 + dx + lm) * 64 + k0);
        acc[nf] = __builtin_amdgcn_mfma_f32_16x16x32_bf16(wf, af, acc[nf], 0, 0, 0);
      }
    }
  }

  // ---- transpose 64px x 64ch through LDS; full-line uint4 stores ----
  int ocb = w * 16 + r4;
#pragma unroll
  for (int nf = 0; nf < 4; ++nf) {
    int ri = nf >> 1, ci = nf & 1;
    int p = ri * 32 + ci * 16 + lm;
    bf16 t[4];
#pragma unroll
    for (int r = 0; r < 4; ++r) {
      float v = acc[nf][r] + bias[ocb + r];
      v = v > 0.f ? v : 0.1f * v;
      t[r] = __float2bfloat16(v);
    }
    *(uint2*)&TS[p * 66 + ocb] = *(const uint2*)t;
  }
  __syncthreads();
  bf16* ob = pbuf(out_id) + ((size_t)b * PHW_ + (size_t)(y0 + 1) * PH_ + x0 + 1) * 64;
#pragma unroll
  for (int it = 0; it < 2; ++it) {
    int i = it * 256 + tid;
    int p = i >> 3, c0 = (i & 7) * 8;
    int ri = p >> 5, xo = p & 31;
    *(uint4*)(ob + ((size_t)ri * PH_ + xo) * 64 + c0) = *(const uint4*)&TS[p * 66 + c0];
  }
}

// ---------------- fused offset-conv + modulated deformable conv ----------------
// grid: (800, B). block 256. One 1x32 px tile.
// Phase 0: CO tile = conv3x3(A2) -> 216x32 f32 in LDS (bias, sigmoid on masks).
// Phase A: offsets/masks from LDS -> regs; bilinear bf16 gathers -> vS (aliases coS).
// Phase B: 18-step MFMA over gathered values; LDS-transposed epilogue.
#define LO16(u) __uint_as_float((u) << 16)
#define HI16(u) __uint_as_float((u) & 0xffff0000u)

__global__ __launch_bounds__(256, 4)
void dcn_k(int x_id, int a2_id, int co_woff, const float* __restrict__ co_bias,
           int wd_off, const float* __restrict__ bias,
           float* __restrict__ outp, int xt_out_id)
{
  const bf16* xT = pbuf(x_id);
  const bf16* WD = g_WD + wd_off;               // [18][4][64][8]
  __shared__ __align__(16) char SHD[37376];
  bf16* vS = (bf16*)SHD;                        // [32][584]   (phases A/B)
  float* coS = (float*)SHD;                     // [216][34]   (phase 0 only)
  int tid = threadIdx.x;
  int b = blockIdx.y;
  int bx = xcdswz(blockIdx.x, 100);
  int h = bx / 5;
  int w0 = (bx % 5) * 32;
  int w = tid >> 6, L = tid & 63, lm = L & 15;
  int k0 = (L >> 4) * 8, r4 = (L >> 4) * 4;
  const bf16* xb = xT + (size_t)b * PHW_ * 64;

  // ---- phase 0: CO tile = conv3x3(A2), 216 oc x 32 px ----
  {
    const bf16* a2 = pbuf(a2_id) + (size_t)b * PHW_ * 64;
    const bf16* wl = g_WB + co_woff + L * 8;
    f32x4 cacc[2][4];
#pragma unroll
    for (int ci = 0; ci < 2; ++ci)
#pragma unroll
      for (int oh = 0; oh < 4; ++oh) cacc[ci][oh] = (f32x4)0.f;

#pragma unroll
    for (int cc = 0; cc < 2; ++cc) {
#pragma unroll
      for (int tap = 0; tap < 9; ++tap) {
        const int dy = tap / 3, dx = tap - dy * 3;
        const int ks = cc * 9 + tap;
        bf16x8 af0 = *(const bf16x8*)(a2 +
            (size_t)((h + dy) * PH_ + w0 + dx + lm) * 64 + cc * 32 + k0);
        bf16x8 af1 = *(const bf16x8*)(a2 +
            (size_t)((h + dy) * PH_ + w0 + 16 + dx + lm) * 64 + cc * 32 + k0);
#pragma unroll
        for (int oh = 0; oh < 4; ++oh) {
          int nt = w * 4 + oh;
          if (nt < 14) {
            bf16x8 wf = *(const bf16x8*)(wl + (size_t)(ks * 14 + nt) * 512);
            cacc[0][oh] = __builtin_amdgcn_mfma_f32_16x16x32_bf16(wf, af0, cacc[0][oh], 0, 0, 0);
            cacc[1][oh] = __builtin_amdgcn_mfma_f32_16x16x32_bf16(wf, af1, cacc[1][oh], 0, 0, 0);
          }
        }
      }
    }
#pragma unroll
    for (int ci = 0; ci < 2; ++ci)
#pragma unroll
      for (int oh = 0; oh < 4; ++oh) {
        int nt = w * 4 + oh;
        if (nt < 14) {
#pragma unroll
          for (int r = 0; r < 4; ++r) {
            int oc = nt * 16 + r4 + r;
            if (oc < 216) {
              float v = cacc[ci][oh][r] + co_bias[oc];
              if (oc >= 144) v = 1.f / (1.f + __expf(-v));
              coS[oc * 34 + ci * 16 + lm] = v;
            }
          }
        }
      }
  }
  __syncthreads();

  // ---- offsets/masks LDS -> regs, then free coS for vS ----
  float oy[9], ox[9], mk[9];
#pragma unroll
  for (int t = 0; t < 9; ++t) {
    int idx = t * 256 + tid;
    int gk = idx >> 5, p = idx & 31;
    oy[t] = coS[(gk * 2) * 34 + p];
    ox[t] = coS[(gk * 2 + 1) * 34 + p];
    mk[t] = coS[(144 + gk) * 34 + p];
  }
  __syncthreads();

  // ---- phase A: bilinear bf16 gathers into vS ----
#pragma unroll
  for (int t = 0; t < 9; ++t) {
    int idx = t * 256 + tid;
    int gk = idx >> 5, p = idx & 31;
    int g = gk / 9, kk = gk - g * 9;
    float pyf = oy[t] + (float)(kk / 3 - 1 + h);
    float pxf = ox[t] + (float)(kk % 3 - 1 + w0 + p);
    float y0f = floorf(pyf), x0f = floorf(pxf);
    float ly = pyf - y0f, lx = pxf - x0f;
    int iy0 = (int)y0f, ix0 = (int)x0f;
    int iy1 = iy0 + 1, ix1 = ix0 + 1;
    float mask = mk[t];
    float w00 = (1.f - ly) * (1.f - lx) * mask;
    float w01 = (1.f - ly) * lx * mask;
    float w10 = ly * (1.f - lx) * mask;
    float w11 = ly * lx * mask;
    if (iy0 < 0 || iy0 >= H_) { w00 = 0.f; w01 = 0.f; }
    if (iy1 < 0 || iy1 >= H_) { w10 = 0.f; w11 = 0.f; }
    if (ix0 < 0 || ix0 >= W_) { w00 = 0.f; w10 = 0.f; }
    if (ix1 < 0 || ix1 >= W_) { w01 = 0.f; w11 = 0.f; }
    int cy0 = min(max(iy0, 0), H_ - 1), cy1 = min(max(iy1, 0), H_ - 1);
    int cx0 = min(max(ix0, 0), W_ - 1), cx1 = min(max(ix1, 0), W_ - 1);
    int gb = g * 8;
    uint4 u00 = *(const uint4*)(xb + ((size_t)(cy0 + 1) * PH_ + cx0 + 1) * 64 + gb);
    uint4 u01 = *(const uint4*)(xb + ((size_t)(cy0 + 1) * PH_ + cx1 + 1) * 64 + gb);
    uint4 u10 = *(const uint4*)(xb + ((size_t)(cy1 + 1) * PH_ + cx0 + 1) * 64 + gb);
    uint4 u11 = *(const uint4*)(xb + ((size_t)(cy1 + 1) * PH_ + cx1 + 1) * 64 + gb);
    bf16 tmp[8];
#define LERP2(ci, A, Bq, Cq, Dq) { \
    float vlo = w00 * LO16(A) + w01 * LO16(Bq) + w10 * LO16(Cq) + w11 * LO16(Dq); \
    float vhi = w00 * HI16(A) + w01 * HI16(Bq) + w10 * HI16(Cq) + w11 * HI16(Dq); \
    tmp[2*(ci)] = __float2bfloat16(vlo); tmp[2*(ci)+1] = __float2bfloat16(vhi); }
    LERP2(0, u00.x, u01.x, u10.x, u11.x);
    LERP2(1, u00.y, u01.y, u10.y, u11.y);
    LERP2(2, u00.z, u01.z, u10.z, u11.z);
    LERP2(3, u00.w, u01.w, u10.w, u11.w);
#undef LERP2
    *(uint4*)&vS[p * 584 + g * 72 + kk * 8] = *(const uint4*)tmp;
  }
  __syncthreads();

  // ---- phase B: MFMA ----
  int mt = w & 1;
  int nb2 = (w >> 1) * 2;
  f32x4 acc2[2];
  acc2[0] = (f32x4)0.f; acc2[1] = (f32x4)0.f;
#pragma unroll 3
  for (int kc = 0; kc < 18; ++kc) {
    bf16x8 a = *(const bf16x8*)&vS[(mt * 16 + lm) * 584 + kc * 32 + k0];
#pragma unroll
    for (int i = 0; i < 2; ++i) {
      bf16x8 bw = *(const bf16x8*)(WD + ((kc * 4 + nb2 + i) * 64 + L) * 8);
      acc2[i] = __builtin_amdgcn_mfma_f32_16x16x32_bf16(a, bw, acc2[i], 0, 0, 0);
    }
  }
  __syncthreads();

  // ---- epilogue through LDS (full-line stores) ----
  float* outS = (float*)vS;          // [64 oc][33]
#pragma unroll
  for (int i = 0; i < 2; ++i)
#pragma unroll
    for (int r = 0; r < 4; ++r) {
      int oc = (nb2 + i) * 16 + lm;
      int px = mt * 16 + (L >> 4) * 4 + r;
      outS[oc * 33 + px] = acc2[i][r];
    }
  __syncthreads();
  if (outp) {
    for (int i = tid; i < 2048; i += 256) {
      int oc = i >> 5, p2 = i & 31;
      float v = outS[oc * 33 + p2] + bias[oc];
      v = v > 0.f ? v : 0.1f * v;
      outp[((size_t)(b * 64 + oc) * H_ + h) * W_ + w0 + p2] = v;
    }
  }
  if (xt_out_id) {
    bf16* xt = pbuf(xt_out_id) + (size_t)b * PHW_ * 64;
    for (int i = tid; i < 2048; i += 256) {
      int p2 = i >> 6, c = i & 63;
      float v = outS[c * 33 + p2] + bias[c];
      v = v > 0.f ? v : 0.1f * v;
      xt[((size_t)(h + 1) * PH_ + w0 + p2 + 1) * 64 + c] = __float2bfloat16(v);
    }
  }
}

extern "C" void kernel_launch(void* const* d_in, const int* in_sizes, int n_in,
                              void* d_out, int out_size, void* d_ws, size_t ws_size,
                              hipStream_t stream) {
  (void)in_sizes; (void)n_in; (void)out_size; (void)d_ws; (void)ws_size;
  const float* nbr    = (const float*)d_in[0];
  const float* ref    = (const float*)d_in[1];
  const float* w_off1 = (const float*)d_in[2];
  const float* b_off1 = (const float*)d_in[3];
  const float* w_off2 = (const float*)d_in[4];
  const float* b_off2 = (const float*)d_in[5];
  const float* w_co   = (const float*)d_in[6];
  const float* b_co   = (const float*)d_in[7];
  const float* w_dcn  = (const float*)d_in[8];
  const float* b_dcn  = (const float*)d_in[9];
  const float* w_coff1= (const float*)d_in[10];
  const float* b_coff1= (const float*)d_in[11];
  const float* w_coff2= (const float*)d_in[12];
  const float* b_coff2= (const float*)d_in[13];
  const float* w_cco  = (const float*)d_in[14];
  const float* b_cco  = (const float*)d_in[15];
  const float* w_cdcn = (const float*)d_in[16];
  const float* b_cdcn = (const float*)d_in[17];

  // conv weights: off1 [0,73728) off2 [73728,110592) co@NTPB14 [110592,239616)
  //               coff1 [239616,313344) coff2 [313344,350208) cco@NTPB14 [350208,479232)
  prep_wfrag<<<288, 256, 0, stream>>>(w_off1, 0, 64, 128, 1, 4);
  prep_wfrag<<<144, 256, 0, stream>>>(w_off2, 73728, 64, 64, 1, 4);
  prep_wfrag<<<504, 256, 0, stream>>>(w_co, 110592, 216, 64, 1, 14);
  prep_wfrag<<<288, 256, 0, stream>>>(w_coff1, 239616, 64, 128, 1, 4);
  prep_wfrag<<<144, 256, 0, stream>>>(w_coff2, 313344, 64, 64, 1, 4);
  prep_wfrag<<<504, 256, 0, stream>>>(w_cco, 350208, 216, 64, 1, 14);
  prep_wdcnfrag<<<144, 256, 0, stream>>>(w_dcn, 0);
  prep_wdcnfrag<<<144, 256, 0, stream>>>(w_cdcn, 36864);

  dim3 blk(256);
  float* out = (float*)d_out;
  // padded NHWC bf16 inputs
  nchw2nhwc_pad<<<dim3(160, 4), blk, 0, stream>>>(nbr, 1);
  nchw2nhwc_pad<<<dim3(160, 4), blk, 0, stream>>>(ref, 2);
  // A1 = lrelu(conv(cat(nbr,ref))); A2 = lrelu(conv(A1))
  conv_nhwc<4><<<dim3(400, 4), blk, 0, stream>>>(1, 2, 2, 0, b_off1, 3);
  conv_nhwc<2><<<dim3(400, 4), blk, 0, stream>>>(3, 3, 2, 73728, b_off2, 4);
  // F1 = lrelu(dcn(Xnbr, conv(A2)))  (fused CO)
  dcn_k<<<dim3(800, 4), blk, 0, stream>>>(1, 4, 110592, b_co, 0, b_dcn, nullptr, 5);
  // cascade
  conv_nhwc<4><<<dim3(400, 4), blk, 0, stream>>>(5, 2, 2, 239616, b_coff1, 3);
  conv_nhwc<2><<<dim3(400, 4), blk, 0, stream>>>(3, 3, 2, 313344, b_coff2, 4);
  // out = lrelu(dcn(F1, conv(A2')))  (fused CO)
  dcn_k<<<dim3(800, 4), blk, 0, stream>>>(5, 4, 350208, b_cco, 36864, b_cdcn, out, 0);
}